// Round 2
// baseline (527.510 us; speedup 1.0000x reference)
//
#include <hip/hip_runtime.h>
#include <math.h>

#define BB 2
#define QQ 4
#define NH 32
#define NKV 8
#define GRP 4      // NH / NKV
#define HD 128
#define DM 4096
#define KVN 4096
#define SL 4100    // KVN + QQ
#define RK 410     // top-k remain
#define NCOLS 6144 // 4096 (Wq) + 1024 (Wk) + 1024 (Wv)
#define K1 ((float)(0.08838834764831845 * 1.4426950408889634))  // (1/sqrt(128))*log2(e)
#define NSC 32
#define SCH 130    // 32*130 = 4160 >= 4100
#define NPC 16     // depth partial chunks (4096/256)
// log2(10000)/64
#define L2T_OVER_64 0.20762050593046014

typedef float f4 __attribute__((ext_vector_type(4)));

__device__ __forceinline__ f4 nt4(const float* p) {
    return __builtin_nontemporal_load((const f4*)p);
}
__device__ __forceinline__ f4 ld4(const float* p) {
    return *(const f4*)p;
}

// ---------------- fused init: proj partials + rope tables + zero accum ----------------
// grid 1153 x 256:
//   blocks [0,96):     QKV projection partial sums, part[16][8][6144] (no atomics)
//   blocks [96,1121):  rope tables (fp64 trig), 1025*256 = SL*64 threads
//   blocks [1121,1153): zero attn (32768) + out (32768)
__global__ __launch_bounds__(256) void k_init(const float* __restrict__ hs,
                                              const float* __restrict__ Wq,
                                              const float* __restrict__ Wk,
                                              const float* __restrict__ Wv,
                                              float* __restrict__ part,
                                              float* __restrict__ cos_t,
                                              float* __restrict__ sin_t,
                                              float* __restrict__ attn,
                                              float* __restrict__ out) {
    int bx = blockIdx.x;
    int tid = threadIdx.x;
    if (bx < 96) {
        // ---- projection partials: 6 col-blocks x 16 depth-chunks of 256 ----
        int xc = bx % 6, yc = bx / 6;
        int c4 = (xc * 256 + tid) * 4;
        int d0 = yc * 256;
        const float* Wp; int ld, cc;
        if (c4 < 4096)      { Wp = Wq; ld = 4096; cc = c4; }
        else if (c4 < 5120) { Wp = Wk; ld = 1024; cc = c4 - 4096; }
        else                { Wp = Wv; ld = 1024; cc = c4 - 5120; }
        __shared__ float hsS[8][256];
        for (int j = tid; j < 2048; j += 256)
            hsS[j >> 8][j & 255] = hs[(size_t)(j >> 8) * DM + d0 + (j & 255)];
        __syncthreads();
        float acc[8][4] = {};
        const float* wp = Wp + (size_t)d0 * ld + cc;
        #pragma unroll 8
        for (int d = 0; d < 256; ++d) {
            f4 w = nt4(wp + (size_t)d * ld);
            #pragma unroll
            for (int r = 0; r < 8; ++r) {
                float hv = hsS[r][d];
                acc[r][0] = fmaf(hv, w.x, acc[r][0]);
                acc[r][1] = fmaf(hv, w.y, acc[r][1]);
                acc[r][2] = fmaf(hv, w.z, acc[r][2]);
                acc[r][3] = fmaf(hv, w.w, acc[r][3]);
            }
        }
        #pragma unroll
        for (int r = 0; r < 8; ++r) {
            f4 st = {acc[r][0], acc[r][1], acc[r][2], acc[r][3]};
            *(f4*)&part[((size_t)(yc * 8 + r)) * NCOLS + c4] = st;
        }
    } else if (bx < 1121) {
        // ---- rope tables ----
        int idx = (bx - 96) * 256 + tid;   // [0, 262400)
        int s = idx >> 6, i = idx & 63;
        double inv = exp2(-(double)i * L2T_OVER_64);
        double f = (double)s * inv;
        double sv, cv;
        sincos(f, &sv, &cv);
        cos_t[idx] = (float)cv;
        sin_t[idx] = (float)sv;
    } else {
        // ---- zero attn + out ----
        int zi = (bx - 1121) * 256 + tid;  // [0, 8192)
        for (int j = zi; j < 65536; j += 8192) {
            if (j < 32768) attn[j] = 0.f;
            else           out[j - 32768] = 0.f;
        }
    }
}

__device__ __forceinline__ float dot8(f4 a, f4 b, f4 qa, f4 qb) {
    return a.x*qa.x + a.y*qa.y + a.z*qa.z + a.w*qa.w
         + b.x*qb.x + b.y*qb.y + b.z*qb.z + b.w*qb.w;
}

// ---------------- draft scores: inline q/kn rope from partials, 4 s-rows per wave-iter ----------------
// grid (64, NSC), block 256
__global__ __launch_bounds__(256) void k_score(const float* __restrict__ part,
                                               const float* __restrict__ k_cache,
                                               const float* __restrict__ cos_t,
                                               const float* __restrict__ sin_t,
                                               float* __restrict__ draft) {
    int bh = blockIdx.x, b = bh >> 5, hh = bh & 31;
    int tid = threadIdx.x, wave = tid >> 6, lane = tid & 63;
    int sgrp = lane >> 4, dq = (lane & 15) * 4;
    int s0 = blockIdx.y * SCH;
    int s1 = s0 + SCH; if (s1 > SL) s1 = SL;
    __shared__ float qS[4][128];
    __shared__ float knS[4][128];
    {
        // each thread: one (qi, i) pair; reduce 16 depth-partials, rope at pos=KVN+qi
        int qi = tid >> 6, i = tid & 63;
        int r = b * 4 + qi;
        int c_lo = hh * 128 + i;
        float xlo = 0.f, xhi = 0.f;
        #pragma unroll
        for (int y = 0; y < NPC; ++y) {
            const float* pp = part + ((size_t)(y * 8 + r)) * NCOLS;
            xlo += pp[c_lo];
            xhi += pp[c_lo + 64];
        }
        float cv = cos_t[(KVN + qi) * 64 + i], sv = sin_t[(KVN + qi) * 64 + i];
        qS[qi][i]      = xlo * cv - xhi * sv;
        qS[qi][i + 64] = xhi * cv + xlo * sv;
        if (s1 > KVN) {   // tail blocks also need the 4 roped new-k rows for this kv-head
            int kh = hh >> 2;
            int cl = 4096 + kh * 128 + i;
            float ylo = 0.f, yhi = 0.f;
            #pragma unroll
            for (int y = 0; y < NPC; ++y) {
                const float* pp = part + ((size_t)(y * 8 + r)) * NCOLS;
                ylo += pp[cl];
                yhi += pp[cl + 64];
            }
            knS[qi][i]      = ylo * cv - yhi * sv;
            knS[qi][i + 64] = yhi * cv + ylo * sv;
        }
    }
    __syncthreads();
    f4 qlo[4], qhi[4];
    #pragma unroll
    for (int qi = 0; qi < 4; ++qi) {
        qlo[qi] = ld4(&qS[qi][dq]);
        qhi[qi] = ld4(&qS[qi][dq + 64]);
    }
    float* db = draft + (size_t)bh * QQ * SL;
    for (int s = s0 + wave * 4 + sgrp; s < s1; s += 16) {
        f4 lo, hi;
        if (s < KVN) {
            const float* kp = k_cache + ((size_t)bh * KVN + s) * HD;
            f4 klo = nt4(kp + dq);
            f4 khi = nt4(kp + dq + 64);
            f4 c4 = ld4(cos_t + (size_t)s * 64 + dq);
            f4 s4 = ld4(sin_t + (size_t)s * 64 + dq);
            lo = klo * c4 - khi * s4;
            hi = khi * c4 + klo * s4;
        } else {
            lo = ld4(&knS[s - KVN][dq]);
            hi = ld4(&knS[s - KVN][dq + 64]);
        }
        float p0 = dot8(lo, hi, qlo[0], qhi[0]);
        float p1 = dot8(lo, hi, qlo[1], qhi[1]);
        float p2 = dot8(lo, hi, qlo[2], qhi[2]);
        float p3 = dot8(lo, hi, qlo[3], qhi[3]);
        #pragma unroll
        for (int off = 8; off; off >>= 1) {
            p0 += __shfl_down(p0, off, 16);
            p1 += __shfl_down(p1, off, 16);
            p2 += __shfl_down(p2, off, 16);
            p3 += __shfl_down(p3, off, 16);
        }
        if ((lane & 15) == 0) {
            db[0 * SL + s] = p0;
            db[1 * SL + s] = p1;
            db[2 * SL + s] = p2;
            db[3 * SL + s] = p3;
        }
    }
}

// ---------------- top-k threshold + exp-sum ----------------
__device__ __forceinline__ unsigned int okey(float f) {
    unsigned int u = __float_as_uint(f);
    return (u & 0x80000000u) ? ~u : (u | 0x80000000u);
}

// grid 256 (one row each), block 512 (8 waves).
// Per-wave privatized histograms; wave-0 shfl suffix-scan bin select (4 barriers/pass);
// one final exp2 sweep for the softmax denominator.
__global__ __launch_bounds__(512) void k_topk(const float* __restrict__ draft,
                                              float* __restrict__ thr,
                                              float* __restrict__ c2) {
    int row = blockIdx.x;
    const f4* sc4 = (const f4*)(draft + (size_t)row * SL);  // 1025 vec4s
    __shared__ unsigned int hist[8][256];
    __shared__ unsigned int cnt[256];
    __shared__ float redf[8];
    __shared__ unsigned int s_prefix;
    __shared__ int s_remain;
    int tid = threadIdx.x, wave = tid >> 6, lane = tid & 63;
    unsigned int* myhist = hist[wave];
    unsigned int prefix = 0;
    int remain = RK;
    for (int pass = 3; pass >= 0; --pass) {
        unsigned int* hflat = &hist[0][0];
        #pragma unroll
        for (int i = 0; i < 4; ++i) hflat[tid + i * 512] = 0;
        __syncthreads();
        int shift = pass * 8;
        for (int i = tid; i < 1025; i += 512) {
            f4 v = sc4[i];
            float vv[4] = {v.x, v.y, v.z, v.w};
            #pragma unroll
            for (int e = 0; e < 4; ++e) {
                unsigned int k = okey(vv[e]);
                if (pass == 3 || (k >> (shift + 8)) == prefix)
                    atomicAdd(&myhist[(k >> shift) & 0xFFu], 1u);
            }
        }
        __syncthreads();
        if (tid < 256) {
            unsigned int t = 0;
            #pragma unroll
            for (int w = 0; w < 8; ++w) t += hist[w][tid];
            cnt[tid] = t;
        }
        __syncthreads();
        if (wave == 0) {
            // lane owns bins [4*lane, 4*lane+4); wave-wide suffix scan via shfl
            int base = lane * 4;
            unsigned int c0 = cnt[base], c1 = cnt[base + 1];
            unsigned int cc2 = cnt[base + 2], c3 = cnt[base + 3];
            unsigned int t3 = c3, t2 = cc2 + t3, t1 = c1 + t2, t0 = c0 + t1;
            unsigned int x = t0;
            #pragma unroll
            for (int off = 1; off < 64; off <<= 1) {
                unsigned int y = __shfl_down(x, off);
                if (lane + off < 64) x += y;
            }
            unsigned int hi = x - t0;   // suffix sum of strictly-higher lanes
            unsigned int R = (unsigned int)remain;
            unsigned int S0 = t0 + hi, S1 = t1 + hi, S2 = t2 + hi, S3 = t3 + hi;
            unsigned int Sv[4] = {S0, S1, S2, S3};
            unsigned int Nv[4] = {S1, S2, S3, hi};
            #pragma unroll
            for (int k = 0; k < 4; ++k) {
                if (Sv[k] >= R && Nv[k] < R) {   // unique crossing
                    unsigned int bin = (unsigned int)(base + k);
                    s_prefix = (pass == 3) ? bin : ((prefix << 8) | bin);
                    s_remain = remain - (int)Nv[k];
                }
            }
        }
        __syncthreads();
        prefix = s_prefix;
        remain = s_remain;
        __syncthreads();
    }
    unsigned int u = (prefix & 0x80000000u) ? (prefix ^ 0x80000000u) : ~prefix;
    float thrv = __uint_as_float(u);
    float ls = 0.f;
    for (int i = tid; i < 1025; i += 512) {
        f4 v = sc4[i];
        if (v.x >= thrv) ls += exp2f(v.x * K1);
        if (v.y >= thrv) ls += exp2f(v.y * K1);
        if (v.z >= thrv) ls += exp2f(v.z * K1);
        if (v.w >= thrv) ls += exp2f(v.w * K1);
    }
    #pragma unroll
    for (int off = 32; off; off >>= 1) ls += __shfl_down(ls, off);
    if (lane == 0) redf[wave] = ls;
    __syncthreads();
    if (tid == 0) {
        float t = redf[0] + redf[1] + redf[2] + redf[3]
                + redf[4] + redf[5] + redf[6] + redf[7];
        thr[row] = thrv;
        c2[row] = -log2f(t);
    }
}

// ---------------- P @ V: inline v_new from partials; skip excluded v-rows ----------------
// grid (64, NSC), block 256
__global__ __launch_bounds__(256) void k_pv(const float* __restrict__ draft,
                                            const float* __restrict__ thr,
                                            const float* __restrict__ c2,
                                            const float* __restrict__ v_cache,
                                            const float* __restrict__ part,
                                            float* __restrict__ attn_acc) {
    int bh = blockIdx.x, b = bh >> 5, hh = bh & 31;
    int tid = threadIdx.x, wave = tid >> 6, lane = tid & 63;
    int sh = lane >> 5, dq = (lane & 31) * 4;
    int s0 = blockIdx.y * SCH;
    int s1 = s0 + SCH; if (s1 > SL) s1 = SL;
    __shared__ float vS[4][128];
    if (s1 > KVN) {   // tail blocks reconstruct the 4 new-v rows from partials
        for (int e = tid; e < 512; e += 256) {
            int qi = e >> 7, dd = e & 127;
            int r = b * 4 + qi, kh = hh >> 2;
            int c = 5120 + kh * 128 + dd;
            float x = 0.f;
            #pragma unroll
            for (int y = 0; y < NPC; ++y)
                x += part[((size_t)(y * 8 + r)) * NCOLS + c];
            vS[qi][dd] = x;
        }
    }
    __syncthreads();
    float thr4[4], c24[4];
    #pragma unroll
    for (int qi = 0; qi < 4; ++qi) {
        thr4[qi] = thr[bh * QQ + qi];
        c24[qi] = c2[bh * QQ + qi];
    }
    const float* sc0 = draft + (size_t)bh * QQ * SL;
    float acc[4][4] = {};
    for (int s = s0 + wave * 2 + sh; s < s1; s += 8) {
        float sv0 = sc0[0 * SL + s];
        float sv1 = sc0[1 * SL + s];
        float sv2 = sc0[2 * SL + s];
        float sv3 = sc0[3 * SL + s];
        bool i0 = sv0 >= thr4[0], i1 = sv1 >= thr4[1];
        bool i2 = sv2 >= thr4[2], i3 = sv3 >= thr4[3];
        if (i0 | i1 | i2 | i3) {    // uniform per 32-lane half -> clean skip
            f4 v4;
            if (s < KVN) v4 = nt4(v_cache + ((size_t)bh * KVN + s) * HD + dq);
            else         v4 = ld4(&vS[s - KVN][dq]);
            float w0 = i0 ? exp2f(fmaf(sv0, K1, c24[0])) : 0.f;
            float w1 = i1 ? exp2f(fmaf(sv1, K1, c24[1])) : 0.f;
            float w2 = i2 ? exp2f(fmaf(sv2, K1, c24[2])) : 0.f;
            float w3 = i3 ? exp2f(fmaf(sv3, K1, c24[3])) : 0.f;
            acc[0][0] = fmaf(w0, v4.x, acc[0][0]); acc[0][1] = fmaf(w0, v4.y, acc[0][1]);
            acc[0][2] = fmaf(w0, v4.z, acc[0][2]); acc[0][3] = fmaf(w0, v4.w, acc[0][3]);
            acc[1][0] = fmaf(w1, v4.x, acc[1][0]); acc[1][1] = fmaf(w1, v4.y, acc[1][1]);
            acc[1][2] = fmaf(w1, v4.z, acc[1][2]); acc[1][3] = fmaf(w1, v4.w, acc[1][3]);
            acc[2][0] = fmaf(w2, v4.x, acc[2][0]); acc[2][1] = fmaf(w2, v4.y, acc[2][1]);
            acc[2][2] = fmaf(w2, v4.z, acc[2][2]); acc[2][3] = fmaf(w2, v4.w, acc[2][3]);
            acc[3][0] = fmaf(w3, v4.x, acc[3][0]); acc[3][1] = fmaf(w3, v4.y, acc[3][1]);
            acc[3][2] = fmaf(w3, v4.z, acc[3][2]); acc[3][3] = fmaf(w3, v4.w, acc[3][3]);
        }
    }
    #pragma unroll
    for (int qi = 0; qi < 4; ++qi)
        #pragma unroll
        for (int e = 0; e < 4; ++e)
            acc[qi][e] += __shfl_down(acc[qi][e], 32);
    __shared__ float accs[4][4][128];   // 8 KB: [wave][qi][d]
    if (lane < 32) {
        #pragma unroll
        for (int qi = 0; qi < 4; ++qi)
            *(float4*)&accs[wave][qi][dq] = make_float4(acc[qi][0], acc[qi][1], acc[qi][2], acc[qi][3]);
    }
    __syncthreads();
    for (int e = tid; e < 512; e += 256) {
        int qi = e >> 7, dd = e & 127;
        float sum = accs[0][qi][dd] + accs[1][qi][dd] + accs[2][qi][dd] + accs[3][qi][dd];
        atomicAdd(&attn_acc[(size_t)(b * QQ + qi) * DM + hh * HD + dd], sum);
    }
}

// ---------------- output projection: out += attn_flat @ Wo ----------------
// grid (8, 32), block 128
__global__ __launch_bounds__(128) void k_oproj(const float* __restrict__ attn_flat,
                                               const float* __restrict__ Wo,
                                               float* __restrict__ out) {
    int tid = threadIdx.x;
    int c4 = (blockIdx.x * 128 + tid) * 4;
    int d0 = blockIdx.y * 128;
    __shared__ float apS[8][128];
    const float* ap = attn_flat + d0;
    #pragma unroll
    for (int r = 0; r < 8; ++r) apS[r][tid] = ap[r * DM + tid];
    __syncthreads();
    float acc[8][4] = {};
    const float* wp = Wo + (size_t)d0 * DM + c4;
    #pragma unroll 8
    for (int d = 0; d < 128; ++d) {
        f4 w = nt4(wp + (size_t)d * DM);
        #pragma unroll
        for (int r = 0; r < 8; ++r) {
            float hv = apS[r][d];
            acc[r][0] = fmaf(hv, w.x, acc[r][0]);
            acc[r][1] = fmaf(hv, w.y, acc[r][1]);
            acc[r][2] = fmaf(hv, w.z, acc[r][2]);
            acc[r][3] = fmaf(hv, w.w, acc[r][3]);
        }
    }
    #pragma unroll
    for (int r = 0; r < 8; ++r)
        #pragma unroll
        for (int e = 0; e < 4; ++e)
            atomicAdd(&out[(size_t)r * DM + c4 + e], acc[r][e]);
}

extern "C" void kernel_launch(void* const* d_in, const int* in_sizes, int n_in,
                              void* d_out, int out_size, void* d_ws, size_t ws_size,
                              hipStream_t stream) {
    const float* hs      = (const float*)d_in[0];
    const float* k_cache = (const float*)d_in[1];
    const float* v_cache = (const float*)d_in[2];
    const float* Wq      = (const float*)d_in[3];
    const float* Wk      = (const float*)d_in[4];
    const float* Wv      = (const float*)d_in[5];
    const float* Wo      = (const float*)d_in[6];
    float* out = (float*)d_out;
    float* ws  = (float*)d_ws;

    float* part  = ws;                 // 786432  (16 x 8 x 6144 partials)
    float* cos_t = ws + 786432;        // 262400
    float* sin_t = ws + 1048832;       // 262400
    float* draft = ws + 1311232;       // 1049600
    float* thr   = ws + 2360832;       // 256
    float* c2    = ws + 2361088;       // 256
    float* attn  = ws + 2361344;       // 32768 -> end 2394112 floats (~9.6 MB)

    k_init<<<dim3(1153), dim3(256), 0, stream>>>(hs, Wq, Wk, Wv, part, cos_t, sin_t, attn, out);
    k_score<<<dim3(BB * NH, NSC), dim3(256), 0, stream>>>(part, k_cache, cos_t, sin_t, draft);
    k_topk<<<dim3(BB * NH * QQ), dim3(512), 0, stream>>>(draft, thr, c2);
    k_pv<<<dim3(BB * NH, NSC), dim3(256), 0, stream>>>(draft, thr, c2, v_cache, part, attn);
    k_oproj<<<dim3(8, 32), dim3(128), 0, stream>>>(attn, Wo, out);
}